// Round 11
// baseline (353.923 us; speedup 1.0000x reference)
//
#include <hip/hip_runtime.h>

// Problem constants (match reference setup_inputs)
#define NN 100000
#define NE 600000
#define NG 256
#define HID 128
#define BN_EPS 1e-5f

#define SCAN_TILE 1024
#define NTILES ((NN + SCAN_TILE - 1) / SCAN_TILE)  // 98
#define MM_TILES (NN / 32)                          // 3125 (NN % 32 == 0)

typedef __attribute__((ext_vector_type(8))) short short8;
typedef __attribute__((ext_vector_type(4))) float float4v;

// bf16 round-to-nearest-even helpers
__device__ __forceinline__ unsigned short f2bf_rn(float f) {
    unsigned u = __float_as_uint(f);
    unsigned r = u + 0x7FFFu + ((u >> 16) & 1u);
    return (unsigned short)(r >> 16);
}
__device__ __forceinline__ float bf2f(unsigned short h) {
    return __uint_as_float((unsigned)h << 16);
}
__device__ __forceinline__ void unpack8(uint4 u, float* f) {
    f[0] = __uint_as_float(u.x << 16); f[1] = __uint_as_float(u.x & 0xFFFF0000u);
    f[2] = __uint_as_float(u.y << 16); f[3] = __uint_as_float(u.y & 0xFFFF0000u);
    f[4] = __uint_as_float(u.z << 16); f[5] = __uint_as_float(u.z & 0xFFFF0000u);
    f[6] = __uint_as_float(u.w << 16); f[7] = __uint_as_float(u.w & 0xFFFF0000u);
}

// ---------------- histogram of dst (in-degree) ----------------

__global__ __launch_bounds__(256) void hist_kernel(const int* __restrict__ dst, int* __restrict__ cnt) {
    int e = blockIdx.x * blockDim.x + threadIdx.x;
    if (e < NE) atomicAdd(&cnt[dst[e]], 1);
}

// ---------------- scan of cnt -> row_start (+ dinv + degree histogram fused) ----------------

__global__ __launch_bounds__(256) void scan_a(const int* __restrict__ cnt, int* __restrict__ rs,
                                              int* __restrict__ tsum, float* __restrict__ dinv,
                                              int* __restrict__ dbin) {
    __shared__ int s[256];
    __shared__ int hb[64];
    int t = threadIdx.x;
    int base = blockIdx.x * SCAN_TILE;
    int idx = base + t * 4;
    int v0 = (idx + 0 < NN) ? cnt[idx + 0] : 0;
    int v1 = (idx + 1 < NN) ? cnt[idx + 1] : 0;
    int v2 = (idx + 2 < NN) ? cnt[idx + 2] : 0;
    int v3 = (idx + 3 < NN) ? cnt[idx + 3] : 0;
    if (idx + 0 < NN) dinv[idx + 0] = rsqrtf((float)v0 + 1.0f);
    if (idx + 1 < NN) dinv[idx + 1] = rsqrtf((float)v1 + 1.0f);
    if (idx + 2 < NN) dinv[idx + 2] = rsqrtf((float)v2 + 1.0f);
    if (idx + 3 < NN) dinv[idx + 3] = rsqrtf((float)v3 + 1.0f);
    int local = v0 + v1 + v2 + v3;
    s[t] = local;
    if (t < 64) hb[t] = 0;
    __syncthreads();
    // LDS degree histogram (clamped to bin 63)
    if (idx + 0 < NN) atomicAdd(&hb[v0 < 63 ? v0 : 63], 1);
    if (idx + 1 < NN) atomicAdd(&hb[v1 < 63 ? v1 : 63], 1);
    if (idx + 2 < NN) atomicAdd(&hb[v2 < 63 ? v2 : 63], 1);
    if (idx + 3 < NN) atomicAdd(&hb[v3 < 63 ? v3 : 63], 1);
    for (int off = 1; off < 256; off <<= 1) {
        int x = (t >= off) ? s[t - off] : 0;
        __syncthreads();
        s[t] += x;
        __syncthreads();
    }
    int pre = s[t] - local;  // exclusive prefix within tile
    if (t == 255) tsum[blockIdx.x] = s[255];
    if (t < 64 && hb[t]) atomicAdd(&dbin[t], hb[t]);
    if (idx + 0 < NN) rs[idx + 0] = pre; pre += v0;
    if (idx + 1 < NN) rs[idx + 1] = pre; pre += v1;
    if (idx + 2 < NN) rs[idx + 2] = pre; pre += v2;
    if (idx + 3 < NN) rs[idx + 3] = pre;
}

// rs finalize + cursor init + degree-binned node permutation (counting sort scatter).

__global__ __launch_bounds__(256) void scan_c(int* __restrict__ rs, const int* __restrict__ tsum,
                                              int* __restrict__ cursor, const int* __restrict__ dbin,
                                              int* __restrict__ dcur, int* __restrict__ perm) {
    __shared__ int s[256];
    __shared__ int pb[64];   // inclusive bin prefix
    __shared__ int lb[64];   // local bin counts -> global base
    int t = threadIdx.x;
    s[t] = (t < (int)blockIdx.x && t < NTILES) ? tsum[t] : 0;
    if (t < 64) { lb[t] = 0; pb[t] = dbin[t]; }
    __syncthreads();
    // tile offset = sum of tsum[0..bid-1]
#pragma unroll
    for (int off = 128; off >= 1; off >>= 1) {
        if (t < off) s[t] += s[t + off];
        __syncthreads();
    }
    int tile_off = s[0];
    // 64-wide inclusive scan of bin histogram
    for (int o = 1; o < 64; o <<= 1) {
        int x = (t < 64 && t >= o) ? pb[t - o] : 0;
        __syncthreads();
        if (t < 64) pb[t] += x;
        __syncthreads();
    }
    int base = blockIdx.x * SCAN_TILE;
    int deg[4], rk[4];
#pragma unroll
    for (int k = 0; k < 4; k++) {
        int idx = base + t * 4 + k;
        deg[k] = 0; rk[k] = 0;
        if (idx < NN) {
            int d = cursor[idx];               // cnt still holds degrees here
            deg[k] = (d < 63) ? d : 63;
            rk[k] = atomicAdd(&lb[deg[k]], 1); // local rank within (block, bin)
        }
    }
    __syncthreads();
    if (t < 64) lb[t] = (pb[t] - dbin[t]) + atomicAdd(&dcur[t], lb[t]);  // global base for this block's bin range
    __syncthreads();
#pragma unroll
    for (int k = 0; k < 4; k++) {
        int idx = base + t * 4 + k;
        if (idx < NN) {
            int v = rs[idx] + tile_off;
            rs[idx] = v;
            cursor[idx] = v;                   // becomes bucket cursor
            perm[lb[deg[k]] + rk[k]] = idx;
        }
    }
    if (blockIdx.x == 0 && t == 0) rs[NN] = NE;
}

// ---------------- bucket edges by dst + prep (fused, independent halves) ----------------

__global__ __launch_bounds__(256) void bucket_prep_kernel(const int* __restrict__ src, const int* __restrict__ dst,
                                                          int* __restrict__ cursor, int* __restrict__ esrc,
                                                          const float* __restrict__ W1, const float* __restrict__ W2,
                                                          unsigned short* __restrict__ w1hi, unsigned short* __restrict__ w1lo,
                                                          unsigned short* __restrict__ w2hi, unsigned short* __restrict__ w2lo,
                                                          const float* __restrict__ pocket,
                                                          const float* __restrict__ pw1, const float* __restrict__ pb1,
                                                          const float* __restrict__ pw2, const float* __restrict__ pb2,
                                                          float* __restrict__ pv, int nb) {
    if ((int)blockIdx.x < nb) {
        int e = blockIdx.x * 256 + threadIdx.x;
        if (e < NE) {
            int pos = atomicAdd(&cursor[dst[e]], 1);
            esrc[pos] = src[e];
        }
    } else if ((int)blockIdx.x < nb + 64) {
        int t = (blockIdx.x - nb) * 256 + threadIdx.x;
        int k = t >> 7, n = t & 127;      // W[k][n]
        int to = n * HID + k;             // Wt[n][k]
        float v1 = W1[t];
        unsigned short h1 = f2bf_rn(v1);
        w1hi[to] = h1;
        w1lo[to] = f2bf_rn(v1 - bf2f(h1));
        float v2 = W2[t];
        unsigned short h2 = f2bf_rn(v2);
        w2hi[to] = h2;
        w2lo[to] = f2bf_rn(v2 - bf2f(h2));
    } else {
        __shared__ float t1[64];
        int j = threadIdx.x;
        if (j < 64) {
            float acc = pb1[j];
            for (int k = 0; k < 28; k++) acc = fmaf(pocket[k], pw1[k * 64 + j], acc);
            t1[j] = fmaxf(acc, 0.f);
        }
        __syncthreads();
        if (j < 64) {
            float acc2 = pb2[j];
            for (int k = 0; k < 64; k++) acc2 = fmaf(t1[k], pw2[k * 64 + j], acc2);
            pv[j] = acc2;
        }
    }
}

// ---------------- deterministic bucket order (register bitonic; R9-proven) ----------------

template<int N>
__device__ __forceinline__ void bitonic_net(int* a) {
#pragma unroll
    for (int k = 2; k <= N; k <<= 1) {
#pragma unroll
        for (int j = k >> 1; j > 0; j >>= 1) {
#pragma unroll
            for (int i = 0; i < N; i++) {
                int l = i ^ j;
                if (l > i) {
                    int x = a[i], y = a[l];
                    bool up = ((i & k) == 0);
                    bool sw = (x > y) == up;
                    a[i] = sw ? y : x;
                    a[l] = sw ? x : y;
                }
            }
        }
    }
}

template<int N>
__device__ __forceinline__ void sort_reg(int* __restrict__ esrc, int e0, int d) {
    int a[N];
#pragma unroll
    for (int i = 0; i < N; i++) a[i] = (i < d) ? esrc[e0 + i] : 0x7FFFFFFF;
    bitonic_net<N>(a);
#pragma unroll
    for (int i = 0; i < N; i++) if (i < d) esrc[e0 + i] = a[i];
}

__global__ __launch_bounds__(256) void sort_buckets(const int* __restrict__ rs,
                                                    int* __restrict__ esrc,
                                                    const int* __restrict__ perm) {
    int slot = blockIdx.x * 256 + threadIdx.x;
    if (slot >= NN) return;
    int n = perm[slot];
    int e0 = rs[n], e1 = rs[n + 1];
    int d = e1 - e0;
    if (d <= 1) return;
    if (d <= 8) {
        sort_reg<8>(esrc, e0, d);
    } else if (d <= 16) {
        sort_reg<16>(esrc, e0, d);
    } else if (d <= 32) {
        sort_reg<32>(esrc, e0, d);
    } else {
        for (int i = e0 + 1; i < e1; i++) {
            int key = esrc[i];
            int j = i - 1;
            while (j >= e0 && esrc[j] > key) { esrc[j + 1] = esrc[j]; j--; }
            esrc[j + 1] = key;
        }
    }
}

// ---------------- 8-deep hl-row gather accumulate (R10 post-mortem fix) ----------------
// Latency-bound scatter: issue 8 independent edge-index loads (clamped to e for
// i>=cnt -> always in-bounds, L2-hot repeat) then 8 independent row loads in
// flight, THEN accumulate in edge order (FMA chains bit-identical to serial).

__device__ __forceinline__ void gather_rows8(const uint4* __restrict__ hlv,
                                             const int* __restrict__ esrc,
                                             const float* __restrict__ dinv,
                                             int e0, int e1, int lane, float di,
                                             float* __restrict__ acc) {
    float v[8];
    int e = e0;
    while (e < e1) {
        int cnt = e1 - e; cnt = cnt > 8 ? 8 : cnt;
        int sidx[8];
#pragma unroll
        for (int i = 0; i < 8; i++) sidx[i] = esrc[(i < cnt) ? e + i : e];
        uint4 rows[8];
#pragma unroll
        for (int i = 0; i < 8; i++) rows[i] = hlv[(size_t)sidx[i] * 16 + lane];
        float wgt[8];
#pragma unroll
        for (int i = 0; i < 8; i++) wgt[i] = dinv[sidx[i]] * di;
#pragma unroll
        for (int i = 0; i < 8; i++) {
            if (i < cnt) {
                unpack8(rows[i], v);
#pragma unroll
                for (int j = 0; j < 8; j++) acc[j] = fmaf(v[j], wgt[i], acc[j]);
            }
        }
        e += cnt;
    }
}

// ---------------- FUSED layer0 + mm1: agg(x)->BN->ReLU->h0(LDS) ->@W1-> hl1 ----------------

__global__ __launch_bounds__(256) void l0mm1_fused(const float* __restrict__ x,
                                                   const int* __restrict__ rs,
                                                   const int* __restrict__ esrc,
                                                   const float* __restrict__ dinv,
                                                   const float* __restrict__ W,
                                                   const float* __restrict__ b,
                                                   const float* __restrict__ gamma,
                                                   const float* __restrict__ beta,
                                                   const float* __restrict__ mean,
                                                   const float* __restrict__ var,
                                                   const unsigned short* __restrict__ Whi,
                                                   const unsigned short* __restrict__ Wlo,
                                                   unsigned short* __restrict__ out) {
    __shared__ float s[32][8];
    __shared__ unsigned short ht[32][136];   // h0 tile, bf16, +8 pad
    int c4 = threadIdx.x & 31;   // phase-2 feature quad
    int r8 = threadIdx.x >> 5;   // phase-2 node-within-8
    float w[7][4];
#pragma unroll
    for (int k = 0; k < 7; k++)
#pragma unroll
        for (int i = 0; i < 4; i++) w[k][i] = W[k * HID + c4 * 4 + i];
    float4 bb = ((const float4*)b)[c4];
    float4 ga = ((const float4*)gamma)[c4];
    float4 be = ((const float4*)beta)[c4];
    float4 me = ((const float4*)mean)[c4];
    float4 va = ((const float4*)var)[c4];
    float4 sc;
    sc.x = ga.x * rsqrtf(va.x + BN_EPS);
    sc.y = ga.y * rsqrtf(va.y + BN_EPS);
    sc.z = ga.z * rsqrtf(va.z + BN_EPS);
    sc.w = ga.w * rsqrtf(va.w + BN_EPS);
    int m = threadIdx.x >> 3, f = threadIdx.x & 7;  // phase-1 mapping
    int n0b = blockIdx.x * 32;
    // phase 1: aggregate x for node n0b+m, feature f
    float acc = 0.f;
    int n = n0b + m;
    if (f < 7) {
        float di = dinv[n];
        acc = x[n * 7 + f] * di * di;
        int e0 = rs[n], e1 = rs[n + 1];
        int e = e0;
        for (; e + 1 < e1; e += 2) {
            int s0 = esrc[e], s1 = esrc[e + 1];
            float w0 = dinv[s0] * di, w1 = dinv[s1] * di;
            float a0 = x[s0 * 7 + f];
            float a1 = x[s1 * 7 + f];
            acc = fmaf(a0, w0, acc);
            acc = fmaf(a1, w1, acc);
        }
        if (e < e1) {
            int s0 = esrc[e];
            acc = fmaf(x[s0 * 7 + f], dinv[s0] * di, acc);
        }
    }
    s[m][f] = acc;
    __syncthreads();
    // phase 2: transform 32 nodes -> h0 tile in LDS (bf16)
#pragma unroll
    for (int g = 0; g < 4; g++) {
        int m2 = g * 8 + r8;
        float o0 = bb.x, o1 = bb.y, o2 = bb.z, o3 = bb.w;
#pragma unroll
        for (int k = 0; k < 7; k++) {
            float xv = s[m2][k];
            o0 = fmaf(xv, w[k][0], o0);
            o1 = fmaf(xv, w[k][1], o1);
            o2 = fmaf(xv, w[k][2], o2);
            o3 = fmaf(xv, w[k][3], o3);
        }
        ushort4 hi4;
        hi4.x = f2bf_rn(fmaxf(fmaf(o0 - me.x, sc.x, be.x), 0.f));
        hi4.y = f2bf_rn(fmaxf(fmaf(o1 - me.y, sc.y, be.y), 0.f));
        hi4.z = f2bf_rn(fmaxf(fmaf(o2 - me.z, sc.z, be.z), 0.f));
        hi4.w = f2bf_rn(fmaxf(fmaf(o3 - me.w, sc.w, be.w), 0.f));
        *(ushort4*)&ht[m2][c4 * 4] = hi4;
    }
    __syncthreads();
    // phase 3: hl1 = h0 @ W1 (proven mm_mfma fragment mapping)
    int wave = threadIdx.x >> 6;
    int lane = threadIdx.x & 63;
    int mrow = lane & 15;
    int quad = lane >> 4;
    int cn0 = wave * 32;
    short8 bh[2][4], bl[2][4];
#pragma unroll
    for (int ct = 0; ct < 2; ct++)
#pragma unroll
        for (int kc = 0; kc < 4; kc++) {
            size_t off = (size_t)(cn0 + ct * 16 + mrow) * HID + kc * 32 + quad * 8;
            bh[ct][kc] = *(const short8*)(Whi + off);
            bl[ct][kc] = *(const short8*)(Wlo + off);
        }
    short8 ah[2][4];
#pragma unroll
    for (int rt = 0; rt < 2; rt++)
#pragma unroll
        for (int kc = 0; kc < 4; kc++)
            ah[rt][kc] = *(const short8*)&ht[rt * 16 + mrow][kc * 32 + quad * 8];
    float4v accm[2][2];
#pragma unroll
    for (int rt = 0; rt < 2; rt++)
#pragma unroll
        for (int ct = 0; ct < 2; ct++) {
            accm[rt][ct].x = 0.f; accm[rt][ct].y = 0.f;
            accm[rt][ct].z = 0.f; accm[rt][ct].w = 0.f;
        }
#pragma unroll
    for (int kc = 0; kc < 4; kc++)
#pragma unroll
        for (int rt = 0; rt < 2; rt++)
#pragma unroll
            for (int ct = 0; ct < 2; ct++) {
                accm[rt][ct] = __builtin_amdgcn_mfma_f32_16x16x32_bf16(ah[rt][kc], bh[ct][kc], accm[rt][ct], 0, 0, 0);
                accm[rt][ct] = __builtin_amdgcn_mfma_f32_16x16x32_bf16(ah[rt][kc], bl[ct][kc], accm[rt][ct], 0, 0, 0);
            }
#pragma unroll
    for (int rt = 0; rt < 2; rt++)
#pragma unroll
        for (int ct = 0; ct < 2; ct++) {
            int col = cn0 + ct * 16 + mrow;
#pragma unroll
            for (int r = 0; r < 4; r++) {
                int row = n0b + rt * 16 + quad * 4 + r;
                out[(size_t)row * HID + col] = f2bf_rn(accm[rt][ct][r]);
            }
        }
}

// ---------------- FUSED gather+mm: h = gBN(hl) (LDS) ->@W-> hl_next ----------------
// Phase 1 = 8-deep gather (R10 fix); phase 2 = proven mm_mfma mapping.

__global__ __launch_bounds__(256) void gmm_fused(const unsigned short* __restrict__ hl,
                                                 const int* __restrict__ rs,
                                                 const int* __restrict__ esrc,
                                                 const float* __restrict__ dinv,
                                                 const float* __restrict__ b,
                                                 const float* __restrict__ gamma,
                                                 const float* __restrict__ beta,
                                                 const float* __restrict__ mean,
                                                 const float* __restrict__ var,
                                                 const unsigned short* __restrict__ Whi,
                                                 const unsigned short* __restrict__ Wlo,
                                                 unsigned short* __restrict__ out) {
    __shared__ unsigned short ht[32][136];   // h tile, bf16, +8 pad
    int lane16 = threadIdx.x & 15;   // 16-B chunk (8 features)
    int nl = threadIdx.x >> 4;       // node-within-16
    int tl = blockIdx.x * 32;
    const uint4* hlv = (const uint4*)hl;
    float4 bA = ((const float4*)b)[lane16 * 2],     bB = ((const float4*)b)[lane16 * 2 + 1];
    float4 gA = ((const float4*)gamma)[lane16 * 2], gB = ((const float4*)gamma)[lane16 * 2 + 1];
    float4 eA = ((const float4*)beta)[lane16 * 2],  eB = ((const float4*)beta)[lane16 * 2 + 1];
    float4 mA = ((const float4*)mean)[lane16 * 2],  mB = ((const float4*)mean)[lane16 * 2 + 1];
    float4 vA = ((const float4*)var)[lane16 * 2],   vB = ((const float4*)var)[lane16 * 2 + 1];
#pragma unroll
    for (int pass = 0; pass < 2; pass++) {
        int nloc = pass * 16 + nl;
        int n = tl + nloc;
        float di = dinv[n];
        float dsq = di * di;
        float acc[8], v[8];
        {
            uint4 sv = hlv[(size_t)n * 16 + lane16];
            unpack8(sv, v);
            acc[0] = fmaf(v[0], dsq, bA.x); acc[1] = fmaf(v[1], dsq, bA.y);
            acc[2] = fmaf(v[2], dsq, bA.z); acc[3] = fmaf(v[3], dsq, bA.w);
            acc[4] = fmaf(v[4], dsq, bB.x); acc[5] = fmaf(v[5], dsq, bB.y);
            acc[6] = fmaf(v[6], dsq, bB.z); acc[7] = fmaf(v[7], dsq, bB.w);
        }
        gather_rows8(hlv, esrc, dinv, rs[n], rs[n + 1], lane16, di, acc);
        float o[8];
        o[0] = fmaxf(fmaf(acc[0] - mA.x, gA.x * rsqrtf(vA.x + BN_EPS), eA.x), 0.f);
        o[1] = fmaxf(fmaf(acc[1] - mA.y, gA.y * rsqrtf(vA.y + BN_EPS), eA.y), 0.f);
        o[2] = fmaxf(fmaf(acc[2] - mA.z, gA.z * rsqrtf(vA.z + BN_EPS), eA.z), 0.f);
        o[3] = fmaxf(fmaf(acc[3] - mA.w, gA.w * rsqrtf(vA.w + BN_EPS), eA.w), 0.f);
        o[4] = fmaxf(fmaf(acc[4] - mB.x, gB.x * rsqrtf(vB.x + BN_EPS), eB.x), 0.f);
        o[5] = fmaxf(fmaf(acc[5] - mB.y, gB.y * rsqrtf(vB.y + BN_EPS), eB.y), 0.f);
        o[6] = fmaxf(fmaf(acc[6] - mB.z, gB.z * rsqrtf(vB.z + BN_EPS), eB.z), 0.f);
        o[7] = fmaxf(fmaf(acc[7] - mB.w, gB.w * rsqrtf(vB.w + BN_EPS), eB.w), 0.f);
        uint4 p;
        p.x = (unsigned)f2bf_rn(o[0]) | ((unsigned)f2bf_rn(o[1]) << 16);
        p.y = (unsigned)f2bf_rn(o[2]) | ((unsigned)f2bf_rn(o[3]) << 16);
        p.z = (unsigned)f2bf_rn(o[4]) | ((unsigned)f2bf_rn(o[5]) << 16);
        p.w = (unsigned)f2bf_rn(o[6]) | ((unsigned)f2bf_rn(o[7]) << 16);
        *(uint4*)&ht[nloc][lane16 * 8] = p;
    }
    __syncthreads();
    // phase 2: hl_next = h @ W (proven mm_mfma mapping)
    int wave = threadIdx.x >> 6;
    int lane = threadIdx.x & 63;
    int mrow = lane & 15;
    int quad = lane >> 4;
    int cn0 = wave * 32;
    short8 bh[2][4], bl[2][4];
#pragma unroll
    for (int ct = 0; ct < 2; ct++)
#pragma unroll
        for (int kc = 0; kc < 4; kc++) {
            size_t off = (size_t)(cn0 + ct * 16 + mrow) * HID + kc * 32 + quad * 8;
            bh[ct][kc] = *(const short8*)(Whi + off);
            bl[ct][kc] = *(const short8*)(Wlo + off);
        }
    short8 ah[2][4];
#pragma unroll
    for (int rt = 0; rt < 2; rt++)
#pragma unroll
        for (int kc = 0; kc < 4; kc++)
            ah[rt][kc] = *(const short8*)&ht[rt * 16 + mrow][kc * 32 + quad * 8];
    float4v accm[2][2];
#pragma unroll
    for (int rt = 0; rt < 2; rt++)
#pragma unroll
        for (int ct = 0; ct < 2; ct++) {
            accm[rt][ct].x = 0.f; accm[rt][ct].y = 0.f;
            accm[rt][ct].z = 0.f; accm[rt][ct].w = 0.f;
        }
#pragma unroll
    for (int kc = 0; kc < 4; kc++)
#pragma unroll
        for (int rt = 0; rt < 2; rt++)
#pragma unroll
            for (int ct = 0; ct < 2; ct++) {
                accm[rt][ct] = __builtin_amdgcn_mfma_f32_16x16x32_bf16(ah[rt][kc], bh[ct][kc], accm[rt][ct], 0, 0, 0);
                accm[rt][ct] = __builtin_amdgcn_mfma_f32_16x16x32_bf16(ah[rt][kc], bl[ct][kc], accm[rt][ct], 0, 0, 0);
            }
#pragma unroll
    for (int rt = 0; rt < 2; rt++)
#pragma unroll
        for (int ct = 0; ct < 2; ct++) {
            int col = cn0 + ct * 16 + mrow;
#pragma unroll
            for (int r = 0; r < 4; r++) {
                int row = tl + rt * 16 + quad * 4 + r;
                out[(size_t)row * HID + col] = f2bf_rn(accm[rt][ct][r]);
            }
        }
}

// ---------------- gather-aggregate + self-loop + bias + BN + ReLU -> bf16 ----------------
// (final layer; 16 lanes/node, 8-deep gather)

__global__ __launch_bounds__(256) void gather_bn(const unsigned short* __restrict__ hl,
                                                 const int* __restrict__ rs,
                                                 const int* __restrict__ esrc,
                                                 const float* __restrict__ dinv,
                                                 const float* __restrict__ b,
                                                 const float* __restrict__ gamma,
                                                 const float* __restrict__ beta,
                                                 const float* __restrict__ mean,
                                                 const float* __restrict__ var,
                                                 unsigned short* __restrict__ ohi) {
    int t = blockIdx.x * blockDim.x + threadIdx.x;
    int lane = t & 15;          // 16-B chunk within 256-B row (8 features)
    int n = t >> 4;
    if (n >= NN) return;
    const uint4* hlv = (const uint4*)hl;  // 16 uint4 per row
    float di = dinv[n];
    float dsq = di * di;

    float acc[8], v[8];
    {
        uint4 sv = hlv[(size_t)n * 16 + lane];
        unpack8(sv, v);
        float4 bA = ((const float4*)b)[lane * 2];
        float4 bB = ((const float4*)b)[lane * 2 + 1];
        acc[0] = fmaf(v[0], dsq, bA.x); acc[1] = fmaf(v[1], dsq, bA.y);
        acc[2] = fmaf(v[2], dsq, bA.z); acc[3] = fmaf(v[3], dsq, bA.w);
        acc[4] = fmaf(v[4], dsq, bB.x); acc[5] = fmaf(v[5], dsq, bB.y);
        acc[6] = fmaf(v[6], dsq, bB.z); acc[7] = fmaf(v[7], dsq, bB.w);
    }

    gather_rows8(hlv, esrc, dinv, rs[n], rs[n + 1], lane, di, acc);

    float4 gA = ((const float4*)gamma)[lane * 2], gB = ((const float4*)gamma)[lane * 2 + 1];
    float4 eA = ((const float4*)beta)[lane * 2],  eB = ((const float4*)beta)[lane * 2 + 1];
    float4 mA = ((const float4*)mean)[lane * 2],  mB = ((const float4*)mean)[lane * 2 + 1];
    float4 vA = ((const float4*)var)[lane * 2],   vB = ((const float4*)var)[lane * 2 + 1];
    float o[8];
    o[0] = fmaxf(fmaf(acc[0] - mA.x, gA.x * rsqrtf(vA.x + BN_EPS), eA.x), 0.f);
    o[1] = fmaxf(fmaf(acc[1] - mA.y, gA.y * rsqrtf(vA.y + BN_EPS), eA.y), 0.f);
    o[2] = fmaxf(fmaf(acc[2] - mA.z, gA.z * rsqrtf(vA.z + BN_EPS), eA.z), 0.f);
    o[3] = fmaxf(fmaf(acc[3] - mA.w, gA.w * rsqrtf(vA.w + BN_EPS), eA.w), 0.f);
    o[4] = fmaxf(fmaf(acc[4] - mB.x, gB.x * rsqrtf(vB.x + BN_EPS), eB.x), 0.f);
    o[5] = fmaxf(fmaf(acc[5] - mB.y, gB.y * rsqrtf(vB.y + BN_EPS), eB.y), 0.f);
    o[6] = fmaxf(fmaf(acc[6] - mB.z, gB.z * rsqrtf(vB.z + BN_EPS), eB.z), 0.f);
    o[7] = fmaxf(fmaf(acc[7] - mB.w, gB.w * rsqrtf(vB.w + BN_EPS), eB.w), 0.f);

    uint4 p;
    p.x = (unsigned)f2bf_rn(o[0]) | ((unsigned)f2bf_rn(o[1]) << 16);
    p.y = (unsigned)f2bf_rn(o[2]) | ((unsigned)f2bf_rn(o[3]) << 16);
    p.z = (unsigned)f2bf_rn(o[4]) | ((unsigned)f2bf_rn(o[5]) << 16);
    p.w = (unsigned)f2bf_rn(o[6]) | ((unsigned)f2bf_rn(o[7]) << 16);
    ((uint4*)ohi)[(size_t)n * 16 + lane] = p;
}

// ---------------- fused global mean pool + classifier (bf16 input) ----------------

__global__ __launch_bounds__(1024) void poolcls_kernel(const unsigned short* __restrict__ h,
                                                       const int* __restrict__ batch,
                                                       const float* __restrict__ pv,
                                                       const float* __restrict__ cw1,
                                                       const float* __restrict__ cb1,
                                                       const float* __restrict__ cw2,
                                                       const float* __restrict__ cb2,
                                                       float* __restrict__ out) {
    int g = blockIdx.x;
    int lane = threadIdx.x & 31;   // 8-B chunk (4 features) within 256-B row
    int row = threadIdx.x >> 5;    // 0..31
    __shared__ int se[2];
    __shared__ float emb[192];
    __shared__ float hid[96];
    if (threadIdx.x < 2) {
        int target = g + threadIdx.x;
        int lo = 0, hi = NN;
        while (lo < hi) {
            int mid = (lo + hi) >> 1;
            if (batch[mid] < target) lo = mid + 1; else hi = mid;
        }
        se[threadIdx.x] = lo;
    }
    if (threadIdx.x < 64) emb[128 + threadIdx.x] = pv[threadIdx.x];
    __syncthreads();
    int start = se[0], end = se[1];
    const uint2* h2 = (const uint2*)h;  // 32 uint2 per row
    float4 acc = make_float4(0.f, 0.f, 0.f, 0.f);
    for (int n = start + row; n < end; n += 32) {
        uint2 u = h2[(size_t)n * 32 + lane];
        acc.x += __uint_as_float(u.x << 16);
        acc.y += __uint_as_float(u.x & 0xFFFF0000u);
        acc.z += __uint_as_float(u.y << 16);
        acc.w += __uint_as_float(u.y & 0xFFFF0000u);
    }
    __shared__ float4 part[32][32];
    part[row][lane] = acc;
    __syncthreads();
#pragma unroll
    for (int off = 16; off >= 1; off >>= 1) {
        if (row < off) {
            float4 a = part[row][lane];
            float4 c = part[row + off][lane];
            a.x += c.x; a.y += c.y; a.z += c.z; a.w += c.w;
            part[row][lane] = a;
        }
        __syncthreads();
    }
    if (row == 0) {
        float inv = 1.0f / fmaxf((float)(end - start), 1.0f);
        float4 a = part[0][lane];
        a.x *= inv; a.y *= inv; a.z *= inv; a.w *= inv;
        ((float4*)emb)[lane] = a;
    }
    __syncthreads();
    int j = threadIdx.x;
    if (j < 96) {
        float a = cb1[j];
        for (int k = 0; k < 192; k++) a = fmaf(emb[k], cw1[k * 96 + j], a);
        hid[j] = fmaxf(a, 0.f) * cw2[j];
    }
    __syncthreads();
    if (j == 0) {
        float s = cb2[0];
        for (int k = 0; k < 96; k++) s += hid[k];
        out[g] = s;
    }
}

extern "C" void kernel_launch(void* const* d_in, const int* in_sizes, int n_in,
                              void* d_out, int out_size, void* d_ws, size_t ws_size,
                              hipStream_t stream) {
    const float* x        = (const float*)d_in[0];
    const int*   eidx     = (const int*)d_in[1];
    const int*   batch    = (const int*)d_in[2];
    const float* pocket   = (const float*)d_in[3];
    const float* W0 = (const float*)d_in[4];
    const float* b0 = (const float*)d_in[5];
    const float* W1 = (const float*)d_in[6];
    const float* b1 = (const float*)d_in[7];
    const float* W2 = (const float*)d_in[8];
    const float* b2 = (const float*)d_in[9];
    const float* bn_gamma = (const float*)d_in[10];
    const float* bn_beta  = (const float*)d_in[11];
    const float* bn_mean  = (const float*)d_in[12];
    const float* bn_var   = (const float*)d_in[13];
    const float* pw1 = (const float*)d_in[14]; const float* pb1 = (const float*)d_in[15];
    const float* pw2 = (const float*)d_in[16]; const float* pb2 = (const float*)d_in[17];
    const float* cw1 = (const float*)d_in[18]; const float* cb1 = (const float*)d_in[19];
    const float* cw2 = (const float*)d_in[20]; const float* cb2 = (const float*)d_in[21];
    float* out = (float*)d_out;

    // Workspace layout (4-byte units):
    float* ws   = (float*)d_ws;
    float* dinv = ws;                                   // NN
    int*   cnt  = (int*)(ws + NN);                      // NN (hist, then cursor)
    int*   rs   = cnt + NN;                             // NN+1
    int*   tsum = rs + NN + 1;                          // 128
    int*   dbin = tsum + 128;                           // 64 (degree histogram)
    int*   dcur = dbin + 64;                            // 64 (bin alloc cursors)
    int*   perm = dcur + 64;                            // NN (degree-sorted node order)
    int*   esrc = perm + NN;                            // NE
    unsigned short* w1hi = (unsigned short*)(esrc + NE);  // 16384 each
    unsigned short* w1lo = w1hi + HID * HID;
    unsigned short* w2hi = w1lo + HID * HID;
    unsigned short* w2lo = w2hi + HID * HID;
    size_t head = (size_t)NN * 2 + (NN + 1) + 128 + 64 + 64 + NN + NE + (4 * HID * HID) / 2;
    head = (head + 3) & ~(size_t)3;                     // 16B align
    unsigned short* A = (unsigned short*)(ws + head);   // NN*HID ushort (bf16)
    unsigned short* B = A + (size_t)NN * HID;           // NN*HID ushort (bf16)
    float* pv   = (float*)(B + (size_t)NN * HID);       // 64

    const int* srcp = eidx;
    const int* dstp = eidx + NE;

    const int NB = (NE + 255) / 256;  // bucket blocks

    // ---- build CSR (by dst) + dinv + degree-binned perm; split W1/W2 + pocket ----
    hipMemsetAsync(cnt, 0, (size_t)(NN + NN + 1 + 128 + 64 + 64) * sizeof(int), stream);
    hist_kernel<<<NB, 256, 0, stream>>>(dstp, cnt);
    scan_a<<<NTILES, 256, 0, stream>>>(cnt, rs, tsum, dinv, dbin);
    scan_c<<<NTILES, 256, 0, stream>>>(rs, tsum, cnt, dbin, dcur, perm);  // cnt becomes cursor
    bucket_prep_kernel<<<NB + 65, 256, 0, stream>>>(srcp, dstp, cnt, esrc,
                                                    W1, W2, w1hi, w1lo, w2hi, w2lo,
                                                    pocket, pw1, pb1, pw2, pb2, pv, NB);
    // deterministic intra-bucket edge order (bit-stable outputs across calls)
    sort_buckets<<<(NN + 255) / 256, 256, 0, stream>>>(rs, esrc, perm);

    // ---- fused layer0+mm1: x -> h0(LDS) -> @W1 -> hl1 (B) ----
    l0mm1_fused<<<MM_TILES, 256, 0, stream>>>(x, rs, esrc, dinv, W0, b0,
                                              bn_gamma + 0 * HID, bn_beta + 0 * HID,
                                              bn_mean + 0 * HID, bn_var + 0 * HID,
                                              w1hi, w1lo, B);
    // ---- fused gather+mm2: hl1 -> h1(LDS) -> @W2 -> hl2 (A) ----
    gmm_fused<<<MM_TILES, 256, 0, stream>>>(B, rs, esrc, dinv, b1,
                                            bn_gamma + 1 * HID, bn_beta + 1 * HID,
                                            bn_mean + 1 * HID, bn_var + 1 * HID,
                                            w2hi, w2lo, A);
    // ---- final gather: hl2 -> h2 (B) ----
    const int GA_BLOCKS = (NN * 16 + 255) / 256;
    gather_bn<<<GA_BLOCKS, 256, 0, stream>>>(
        A, rs, esrc, dinv, b2,
        bn_gamma + 2 * HID, bn_beta + 2 * HID, bn_mean + 2 * HID, bn_var + 2 * HID, B);

    // fused pool + classifier (bf16 h2)
    poolcls_kernel<<<NG, 1024, 0, stream>>>(B, batch, pv, cw1, cb1, cw2, cb2, out);
}

// Round 14
// 345.659 us; speedup vs baseline: 1.0239x; 1.0239x over previous
//
#include <hip/hip_runtime.h>

// Problem constants (match reference setup_inputs)
#define NN 100000
#define NE 600000
#define NG 256
#define HID 128
#define BN_EPS 1e-5f

#define SCAN_TILE 1024
#define NTILES ((NN + SCAN_TILE - 1) / SCAN_TILE)  // 98
#define MM_TILES (NN / 32)                          // 3125 (NN % 32 == 0)

typedef __attribute__((ext_vector_type(8))) short short8;
typedef __attribute__((ext_vector_type(4))) float float4v;

// bf16 round-to-nearest-even helpers
__device__ __forceinline__ unsigned short f2bf_rn(float f) {
    unsigned u = __float_as_uint(f);
    unsigned r = u + 0x7FFFu + ((u >> 16) & 1u);
    return (unsigned short)(r >> 16);
}
__device__ __forceinline__ float bf2f(unsigned short h) {
    return __uint_as_float((unsigned)h << 16);
}
__device__ __forceinline__ void unpack8(uint4 u, float* f) {
    f[0] = __uint_as_float(u.x << 16); f[1] = __uint_as_float(u.x & 0xFFFF0000u);
    f[2] = __uint_as_float(u.y << 16); f[3] = __uint_as_float(u.y & 0xFFFF0000u);
    f[4] = __uint_as_float(u.z << 16); f[5] = __uint_as_float(u.z & 0xFFFF0000u);
    f[6] = __uint_as_float(u.w << 16); f[7] = __uint_as_float(u.w & 0xFFFF0000u);
}

// ---------------- histogram of dst (in-degree) ----------------

__global__ __launch_bounds__(256) void hist_kernel(const int* __restrict__ dst, int* __restrict__ cnt) {
    int e = blockIdx.x * blockDim.x + threadIdx.x;
    if (e < NE) atomicAdd(&cnt[dst[e]], 1);
}

// ---------------- scan of cnt -> row_start (+ dinv + degree histogram fused) ----------------

__global__ __launch_bounds__(256) void scan_a(const int* __restrict__ cnt, int* __restrict__ rs,
                                              int* __restrict__ tsum, float* __restrict__ dinv,
                                              int* __restrict__ dbin) {
    __shared__ int s[256];
    __shared__ int hb[64];
    int t = threadIdx.x;
    int base = blockIdx.x * SCAN_TILE;
    int idx = base + t * 4;
    int v0 = (idx + 0 < NN) ? cnt[idx + 0] : 0;
    int v1 = (idx + 1 < NN) ? cnt[idx + 1] : 0;
    int v2 = (idx + 2 < NN) ? cnt[idx + 2] : 0;
    int v3 = (idx + 3 < NN) ? cnt[idx + 3] : 0;
    if (idx + 0 < NN) dinv[idx + 0] = rsqrtf((float)v0 + 1.0f);
    if (idx + 1 < NN) dinv[idx + 1] = rsqrtf((float)v1 + 1.0f);
    if (idx + 2 < NN) dinv[idx + 2] = rsqrtf((float)v2 + 1.0f);
    if (idx + 3 < NN) dinv[idx + 3] = rsqrtf((float)v3 + 1.0f);
    int local = v0 + v1 + v2 + v3;
    s[t] = local;
    if (t < 64) hb[t] = 0;
    __syncthreads();
    // LDS degree histogram (clamped to bin 63)
    if (idx + 0 < NN) atomicAdd(&hb[v0 < 63 ? v0 : 63], 1);
    if (idx + 1 < NN) atomicAdd(&hb[v1 < 63 ? v1 : 63], 1);
    if (idx + 2 < NN) atomicAdd(&hb[v2 < 63 ? v2 : 63], 1);
    if (idx + 3 < NN) atomicAdd(&hb[v3 < 63 ? v3 : 63], 1);
    for (int off = 1; off < 256; off <<= 1) {
        int x = (t >= off) ? s[t - off] : 0;
        __syncthreads();
        s[t] += x;
        __syncthreads();
    }
    int pre = s[t] - local;  // exclusive prefix within tile
    if (t == 255) tsum[blockIdx.x] = s[255];
    if (t < 64 && hb[t]) atomicAdd(&dbin[t], hb[t]);
    if (idx + 0 < NN) rs[idx + 0] = pre; pre += v0;
    if (idx + 1 < NN) rs[idx + 1] = pre; pre += v1;
    if (idx + 2 < NN) rs[idx + 2] = pre; pre += v2;
    if (idx + 3 < NN) rs[idx + 3] = pre;
}

// rs finalize + cursor init + degree-binned node permutation (counting sort scatter).
// perm feeds the bucket-sort kernel's load balance (equal-degree waves);
// compute kernels use direct node order.

__global__ __launch_bounds__(256) void scan_c(int* __restrict__ rs, const int* __restrict__ tsum,
                                              int* __restrict__ cursor, const int* __restrict__ dbin,
                                              int* __restrict__ dcur, int* __restrict__ perm) {
    __shared__ int s[256];
    __shared__ int pb[64];   // inclusive bin prefix
    __shared__ int lb[64];   // local bin counts -> global base
    int t = threadIdx.x;
    s[t] = (t < (int)blockIdx.x && t < NTILES) ? tsum[t] : 0;
    if (t < 64) { lb[t] = 0; pb[t] = dbin[t]; }
    __syncthreads();
    // tile offset = sum of tsum[0..bid-1]
#pragma unroll
    for (int off = 128; off >= 1; off >>= 1) {
        if (t < off) s[t] += s[t + off];
        __syncthreads();
    }
    int tile_off = s[0];
    // 64-wide inclusive scan of bin histogram
    for (int o = 1; o < 64; o <<= 1) {
        int x = (t < 64 && t >= o) ? pb[t - o] : 0;
        __syncthreads();
        if (t < 64) pb[t] += x;
        __syncthreads();
    }
    int base = blockIdx.x * SCAN_TILE;
    int deg[4], rk[4];
#pragma unroll
    for (int k = 0; k < 4; k++) {
        int idx = base + t * 4 + k;
        deg[k] = 0; rk[k] = 0;
        if (idx < NN) {
            int d = cursor[idx];               // cnt still holds degrees here
            deg[k] = (d < 63) ? d : 63;
            rk[k] = atomicAdd(&lb[deg[k]], 1); // local rank within (block, bin)
        }
    }
    __syncthreads();
    if (t < 64) lb[t] = (pb[t] - dbin[t]) + atomicAdd(&dcur[t], lb[t]);  // global base for this block's bin range
    __syncthreads();
#pragma unroll
    for (int k = 0; k < 4; k++) {
        int idx = base + t * 4 + k;
        if (idx < NN) {
            int v = rs[idx] + tile_off;
            rs[idx] = v;
            cursor[idx] = v;                   // becomes bucket cursor
            perm[lb[deg[k]] + rk[k]] = idx;
        }
    }
    if (blockIdx.x == 0 && t == 0) rs[NN] = NE;
}

// ---------------- bucket edges by dst + prep (fused, independent halves) ----------------

__global__ __launch_bounds__(256) void bucket_prep_kernel(const int* __restrict__ src, const int* __restrict__ dst,
                                                          int* __restrict__ cursor, int* __restrict__ esrc,
                                                          const float* __restrict__ W1, const float* __restrict__ W2,
                                                          unsigned short* __restrict__ w1hi, unsigned short* __restrict__ w1lo,
                                                          unsigned short* __restrict__ w2hi, unsigned short* __restrict__ w2lo,
                                                          const float* __restrict__ pocket,
                                                          const float* __restrict__ pw1, const float* __restrict__ pb1,
                                                          const float* __restrict__ pw2, const float* __restrict__ pb2,
                                                          float* __restrict__ pv, int nb) {
    if ((int)blockIdx.x < nb) {
        int e = blockIdx.x * 256 + threadIdx.x;
        if (e < NE) {
            int pos = atomicAdd(&cursor[dst[e]], 1);
            esrc[pos] = src[e];
        }
    } else if ((int)blockIdx.x < nb + 64) {
        int t = (blockIdx.x - nb) * 256 + threadIdx.x;
        int k = t >> 7, n = t & 127;      // W[k][n]
        int to = n * HID + k;             // Wt[n][k]
        float v1 = W1[t];
        unsigned short h1 = f2bf_rn(v1);
        w1hi[to] = h1;
        w1lo[to] = f2bf_rn(v1 - bf2f(h1));
        float v2 = W2[t];
        unsigned short h2 = f2bf_rn(v2);
        w2hi[to] = h2;
        w2lo[to] = f2bf_rn(v2 - bf2f(h2));
    } else {
        __shared__ float t1[64];
        int j = threadIdx.x;
        if (j < 64) {
            float acc = pb1[j];
            for (int k = 0; k < 28; k++) acc = fmaf(pocket[k], pw1[k * 64 + j], acc);
            t1[j] = fmaxf(acc, 0.f);
        }
        __syncthreads();
        if (j < 64) {
            float acc2 = pb2[j];
            for (int k = 0; k < 64; k++) acc2 = fmaf(t1[k], pw2[k * 64 + j], acc2);
            pv[j] = acc2;
        }
    }
}

// ---------------- deterministic bucket order (register bitonic; R9-proven) ----------------

template<int N>
__device__ __forceinline__ void bitonic_net(int* a) {
#pragma unroll
    for (int k = 2; k <= N; k <<= 1) {
#pragma unroll
        for (int j = k >> 1; j > 0; j >>= 1) {
#pragma unroll
            for (int i = 0; i < N; i++) {
                int l = i ^ j;
                if (l > i) {
                    int x = a[i], y = a[l];
                    bool up = ((i & k) == 0);
                    bool sw = (x > y) == up;
                    a[i] = sw ? y : x;
                    a[l] = sw ? x : y;
                }
            }
        }
    }
}

template<int N>
__device__ __forceinline__ void sort_reg(int* __restrict__ esrc, int e0, int d) {
    int a[N];
#pragma unroll
    for (int i = 0; i < N; i++) a[i] = (i < d) ? esrc[e0 + i] : 0x7FFFFFFF;
    bitonic_net<N>(a);
#pragma unroll
    for (int i = 0; i < N; i++) if (i < d) esrc[e0 + i] = a[i];
}

__global__ __launch_bounds__(256) void sort_buckets(const int* __restrict__ rs,
                                                    int* __restrict__ esrc,
                                                    const int* __restrict__ perm) {
    int slot = blockIdx.x * 256 + threadIdx.x;
    if (slot >= NN) return;
    int n = perm[slot];
    int e0 = rs[n], e1 = rs[n + 1];
    int d = e1 - e0;
    if (d <= 1) return;
    if (d <= 8) {
        sort_reg<8>(esrc, e0, d);
    } else if (d <= 16) {
        sort_reg<16>(esrc, e0, d);
    } else if (d <= 32) {
        sort_reg<32>(esrc, e0, d);
    } else {
        for (int i = e0 + 1; i < e1; i++) {
            int key = esrc[i];
            int j = i - 1;
            while (j >= e0 && esrc[j] > key) { esrc[j + 1] = esrc[j]; j--; }
            esrc[j + 1] = key;
        }
    }
}

// ---------------- layer 0 fused: agg(x) -> @W0 -> BN -> ReLU -> bf16 ----------------

__global__ __launch_bounds__(256) void l0_fused(const float* __restrict__ x,
                                                const int* __restrict__ rs,
                                                const int* __restrict__ esrc,
                                                const float* __restrict__ dinv,
                                                const float* __restrict__ W,
                                                const float* __restrict__ b,
                                                const float* __restrict__ gamma,
                                                const float* __restrict__ beta,
                                                const float* __restrict__ mean,
                                                const float* __restrict__ var,
                                                unsigned short* __restrict__ ohi) {
    int c4 = threadIdx.x & 31;   // phase-2 feature quad
    int r8 = threadIdx.x >> 5;   // phase-2 node-within-8
    float w[7][4];
#pragma unroll
    for (int k = 0; k < 7; k++)
#pragma unroll
        for (int i = 0; i < 4; i++) w[k][i] = W[k * HID + c4 * 4 + i];
    float4 bb = ((const float4*)b)[c4];
    float4 ga = ((const float4*)gamma)[c4];
    float4 be = ((const float4*)beta)[c4];
    float4 me = ((const float4*)mean)[c4];
    float4 va = ((const float4*)var)[c4];
    float4 sc;
    sc.x = ga.x * rsqrtf(va.x + BN_EPS);
    sc.y = ga.y * rsqrtf(va.y + BN_EPS);
    sc.z = ga.z * rsqrtf(va.z + BN_EPS);
    sc.w = ga.w * rsqrtf(va.w + BN_EPS);
    int m = threadIdx.x >> 3, f = threadIdx.x & 7;  // phase-1 mapping
    __shared__ float s[32][8];
    int n0 = blockIdx.x * 32;
    // phase 1: aggregate x for node n0+m, feature f (NN % 32 == 0)
    float acc = 0.f;
    int n = n0 + m;
    if (f < 7) {
        float di = dinv[n];
        acc = x[n * 7 + f] * di * di;
        int e0 = rs[n], e1 = rs[n + 1];
        int e = e0;
        for (; e + 1 < e1; e += 2) {
            int s0 = esrc[e], s1 = esrc[e + 1];
            float w0 = dinv[s0] * di, w1 = dinv[s1] * di;
            float a0 = x[s0 * 7 + f];
            float a1 = x[s1 * 7 + f];
            acc = fmaf(a0, w0, acc);
            acc = fmaf(a1, w1, acc);
        }
        if (e < e1) {
            int s0 = esrc[e];
            acc = fmaf(x[s0 * 7 + f], dinv[s0] * di, acc);
        }
    }
    s[m][f] = acc;
    __syncthreads();
    // phase 2: transform 32 nodes, 8 per iteration
#pragma unroll
    for (int g = 0; g < 4; g++) {
        int m2 = g * 8 + r8;
        float o0 = bb.x, o1 = bb.y, o2 = bb.z, o3 = bb.w;
#pragma unroll
        for (int k = 0; k < 7; k++) {
            float xv = s[m2][k];
            o0 = fmaf(xv, w[k][0], o0);
            o1 = fmaf(xv, w[k][1], o1);
            o2 = fmaf(xv, w[k][2], o2);
            o3 = fmaf(xv, w[k][3], o3);
        }
        ushort4 hi4;
        hi4.x = f2bf_rn(fmaxf(fmaf(o0 - me.x, sc.x, be.x), 0.f));
        hi4.y = f2bf_rn(fmaxf(fmaf(o1 - me.y, sc.y, be.y), 0.f));
        hi4.z = f2bf_rn(fmaxf(fmaf(o2 - me.z, sc.z, be.z), 0.f));
        hi4.w = f2bf_rn(fmaxf(fmaf(o3 - me.w, sc.w, be.w), 0.f));
        *(ushort4*)(ohi + (size_t)(n0 + m2) * HID + c4 * 4) = hi4;
    }
}

// ---------------- layers 1/2 matmul via MFMA ----------------
// Persistent blocks (grid 1024, ~3 tiles each); W hi/lo fragments
// register-resident; next tile's A fragments prefetched during compute.

__global__ __launch_bounds__(256) void mm_mfma(const unsigned short* __restrict__ A,
                                               const unsigned short* __restrict__ Whi,
                                               const unsigned short* __restrict__ Wlo,
                                               unsigned short* __restrict__ out) {
    int wave = threadIdx.x >> 6;
    int lane = threadIdx.x & 63;
    int mrow = lane & 15;
    int quad = lane >> 4;
    int n0 = wave * 32;

    short8 bh[2][4], bl[2][4];
#pragma unroll
    for (int ct = 0; ct < 2; ct++) {
#pragma unroll
        for (int kc = 0; kc < 4; kc++) {
            size_t off = (size_t)(n0 + ct * 16 + mrow) * HID + kc * 32 + quad * 8;
            bh[ct][kc] = *(const short8*)(Whi + off);
            bl[ct][kc] = *(const short8*)(Wlo + off);
        }
    }

    int tile = blockIdx.x;
    if (tile >= MM_TILES) return;

    short8 ah[2][4];
#pragma unroll
    for (int rt = 0; rt < 2; rt++)
#pragma unroll
        for (int kc = 0; kc < 4; kc++)
            ah[rt][kc] = *(const short8*)(A + (size_t)(tile * 32 + rt * 16 + mrow) * HID + kc * 32 + quad * 8);

    for (;;) {
        int nt = tile + gridDim.x;
        bool has_next = nt < MM_TILES;
        short8 an[2][4];
        if (has_next) {
#pragma unroll
            for (int rt = 0; rt < 2; rt++)
#pragma unroll
                for (int kc = 0; kc < 4; kc++)
                    an[rt][kc] = *(const short8*)(A + (size_t)(nt * 32 + rt * 16 + mrow) * HID + kc * 32 + quad * 8);
        }

        float4v acc[2][2];
#pragma unroll
        for (int rt = 0; rt < 2; rt++)
#pragma unroll
            for (int ct = 0; ct < 2; ct++) {
                acc[rt][ct].x = 0.f; acc[rt][ct].y = 0.f;
                acc[rt][ct].z = 0.f; acc[rt][ct].w = 0.f;
            }

#pragma unroll
        for (int kc = 0; kc < 4; kc++)
#pragma unroll
            for (int rt = 0; rt < 2; rt++)
#pragma unroll
                for (int ct = 0; ct < 2; ct++) {
                    acc[rt][ct] = __builtin_amdgcn_mfma_f32_16x16x32_bf16(ah[rt][kc], bh[ct][kc], acc[rt][ct], 0, 0, 0);
                    acc[rt][ct] = __builtin_amdgcn_mfma_f32_16x16x32_bf16(ah[rt][kc], bl[ct][kc], acc[rt][ct], 0, 0, 0);
                }

        int m0 = tile * 32;
#pragma unroll
        for (int rt = 0; rt < 2; rt++)
#pragma unroll
            for (int ct = 0; ct < 2; ct++) {
                int col = n0 + ct * 16 + mrow;
#pragma unroll
                for (int r = 0; r < 4; r++) {
                    int row = m0 + rt * 16 + quad * 4 + r;
                    out[(size_t)row * HID + col] = f2bf_rn(acc[rt][ct][r]);
                }
            }

        if (!has_next) break;
#pragma unroll
        for (int rt = 0; rt < 2; rt++)
#pragma unroll
            for (int kc = 0; kc < 4; kc++) ah[rt][kc] = an[rt][kc];
        tile = nt;
    }
}

// ---------------- gather-aggregate + self-loop + bias + BN + ReLU -> bf16 ----------------
// 16 lanes/node, uint4 gathers. R11 fix: clamped 4-deep batch — every group of
// <=4 edges issues 4 INDEPENDENT index loads (clamped in-bounds, L2-hot) then 4
// independent row loads, then accumulates in edge order (bit-identical chains).
// Removes the serial dependent tail without the rows[8] VGPR cost.

__global__ __launch_bounds__(256) void gather_bn(const unsigned short* __restrict__ hl,
                                                 const int* __restrict__ rs,
                                                 const int* __restrict__ esrc,
                                                 const float* __restrict__ dinv,
                                                 const float* __restrict__ b,
                                                 const float* __restrict__ gamma,
                                                 const float* __restrict__ beta,
                                                 const float* __restrict__ mean,
                                                 const float* __restrict__ var,
                                                 unsigned short* __restrict__ ohi) {
    int t = blockIdx.x * blockDim.x + threadIdx.x;
    int lane = t & 15;          // 16-B chunk within 256-B row (8 features)
    int n = t >> 4;
    if (n >= NN) return;
    const uint4* hlv = (const uint4*)hl;  // 16 uint4 per row
    float di = dinv[n];
    float dsq = di * di;

    float acc[8], v[8];
    {
        uint4 sv = hlv[(size_t)n * 16 + lane];
        unpack8(sv, v);
        float4 bA = ((const float4*)b)[lane * 2];
        float4 bB = ((const float4*)b)[lane * 2 + 1];
        acc[0] = fmaf(v[0], dsq, bA.x); acc[1] = fmaf(v[1], dsq, bA.y);
        acc[2] = fmaf(v[2], dsq, bA.z); acc[3] = fmaf(v[3], dsq, bA.w);
        acc[4] = fmaf(v[4], dsq, bB.x); acc[5] = fmaf(v[5], dsq, bB.y);
        acc[6] = fmaf(v[6], dsq, bB.z); acc[7] = fmaf(v[7], dsq, bB.w);
    }

    int e0 = rs[n], e1 = rs[n + 1];
    int e = e0;
    while (e < e1) {
        int cnt = e1 - e; cnt = cnt > 4 ? 4 : cnt;
        int sidx[4];
#pragma unroll
        for (int i = 0; i < 4; i++) sidx[i] = esrc[(i < cnt) ? e + i : e];
        uint4 rows[4];
#pragma unroll
        for (int i = 0; i < 4; i++) rows[i] = hlv[(size_t)sidx[i] * 16 + lane];
        float wgt[4];
#pragma unroll
        for (int i = 0; i < 4; i++) wgt[i] = dinv[sidx[i]] * di;
#pragma unroll
        for (int i = 0; i < 4; i++) {
            if (i < cnt) {
                unpack8(rows[i], v);
#pragma unroll
                for (int j = 0; j < 8; j++) acc[j] = fmaf(v[j], wgt[i], acc[j]);
            }
        }
        e += cnt;
    }

    float4 gA = ((const float4*)gamma)[lane * 2], gB = ((const float4*)gamma)[lane * 2 + 1];
    float4 eA = ((const float4*)beta)[lane * 2],  eB = ((const float4*)beta)[lane * 2 + 1];
    float4 mA = ((const float4*)mean)[lane * 2],  mB = ((const float4*)mean)[lane * 2 + 1];
    float4 vA = ((const float4*)var)[lane * 2],   vB = ((const float4*)var)[lane * 2 + 1];
    float o[8];
    o[0] = fmaxf(fmaf(acc[0] - mA.x, gA.x * rsqrtf(vA.x + BN_EPS), eA.x), 0.f);
    o[1] = fmaxf(fmaf(acc[1] - mA.y, gA.y * rsqrtf(vA.y + BN_EPS), eA.y), 0.f);
    o[2] = fmaxf(fmaf(acc[2] - mA.z, gA.z * rsqrtf(vA.z + BN_EPS), eA.z), 0.f);
    o[3] = fmaxf(fmaf(acc[3] - mA.w, gA.w * rsqrtf(vA.w + BN_EPS), eA.w), 0.f);
    o[4] = fmaxf(fmaf(acc[4] - mB.x, gB.x * rsqrtf(vB.x + BN_EPS), eB.x), 0.f);
    o[5] = fmaxf(fmaf(acc[5] - mB.y, gB.y * rsqrtf(vB.y + BN_EPS), eB.y), 0.f);
    o[6] = fmaxf(fmaf(acc[6] - mB.z, gB.z * rsqrtf(vB.z + BN_EPS), eB.z), 0.f);
    o[7] = fmaxf(fmaf(acc[7] - mB.w, gB.w * rsqrtf(vB.w + BN_EPS), eB.w), 0.f);

    uint4 p;
    p.x = (unsigned)f2bf_rn(o[0]) | ((unsigned)f2bf_rn(o[1]) << 16);
    p.y = (unsigned)f2bf_rn(o[2]) | ((unsigned)f2bf_rn(o[3]) << 16);
    p.z = (unsigned)f2bf_rn(o[4]) | ((unsigned)f2bf_rn(o[5]) << 16);
    p.w = (unsigned)f2bf_rn(o[6]) | ((unsigned)f2bf_rn(o[7]) << 16);
    ((uint4*)ohi)[(size_t)n * 16 + lane] = p;
}

// ---------------- fused global mean pool + classifier (bf16 input) ----------------

__global__ __launch_bounds__(1024) void poolcls_kernel(const unsigned short* __restrict__ h,
                                                       const int* __restrict__ batch,
                                                       const float* __restrict__ pv,
                                                       const float* __restrict__ cw1,
                                                       const float* __restrict__ cb1,
                                                       const float* __restrict__ cw2,
                                                       const float* __restrict__ cb2,
                                                       float* __restrict__ out) {
    int g = blockIdx.x;
    int lane = threadIdx.x & 31;   // 8-B chunk (4 features) within 256-B row
    int row = threadIdx.x >> 5;    // 0..31
    __shared__ int se[2];
    __shared__ float emb[192];
    __shared__ float hid[96];
    if (threadIdx.x < 2) {
        int target = g + threadIdx.x;
        int lo = 0, hi = NN;
        while (lo < hi) {
            int mid = (lo + hi) >> 1;
            if (batch[mid] < target) lo = mid + 1; else hi = mid;
        }
        se[threadIdx.x] = lo;
    }
    if (threadIdx.x < 64) emb[128 + threadIdx.x] = pv[threadIdx.x];
    __syncthreads();
    int start = se[0], end = se[1];
    const uint2* h2 = (const uint2*)h;  // 32 uint2 per row
    float4 acc = make_float4(0.f, 0.f, 0.f, 0.f);
    for (int n = start + row; n < end; n += 32) {
        uint2 u = h2[(size_t)n * 32 + lane];
        acc.x += __uint_as_float(u.x << 16);
        acc.y += __uint_as_float(u.x & 0xFFFF0000u);
        acc.z += __uint_as_float(u.y << 16);
        acc.w += __uint_as_float(u.y & 0xFFFF0000u);
    }
    __shared__ float4 part[32][32];
    part[row][lane] = acc;
    __syncthreads();
#pragma unroll
    for (int off = 16; off >= 1; off >>= 1) {
        if (row < off) {
            float4 a = part[row][lane];
            float4 c = part[row + off][lane];
            a.x += c.x; a.y += c.y; a.z += c.z; a.w += c.w;
            part[row][lane] = a;
        }
        __syncthreads();
    }
    if (row == 0) {
        float inv = 1.0f / fmaxf((float)(end - start), 1.0f);
        float4 a = part[0][lane];
        a.x *= inv; a.y *= inv; a.z *= inv; a.w *= inv;
        ((float4*)emb)[lane] = a;
    }
    __syncthreads();
    int j = threadIdx.x;
    if (j < 96) {
        float a = cb1[j];
        for (int k = 0; k < 192; k++) a = fmaf(emb[k], cw1[k * 96 + j], a);
        hid[j] = fmaxf(a, 0.f) * cw2[j];
    }
    __syncthreads();
    if (j == 0) {
        float s = cb2[0];
        for (int k = 0; k < 96; k++) s += hid[k];
        out[g] = s;
    }
}

extern "C" void kernel_launch(void* const* d_in, const int* in_sizes, int n_in,
                              void* d_out, int out_size, void* d_ws, size_t ws_size,
                              hipStream_t stream) {
    const float* x        = (const float*)d_in[0];
    const int*   eidx     = (const int*)d_in[1];
    const int*   batch    = (const int*)d_in[2];
    const float* pocket   = (const float*)d_in[3];
    const float* W0 = (const float*)d_in[4];
    const float* b0 = (const float*)d_in[5];
    const float* W1 = (const float*)d_in[6];
    const float* b1 = (const float*)d_in[7];
    const float* W2 = (const float*)d_in[8];
    const float* b2 = (const float*)d_in[9];
    const float* bn_gamma = (const float*)d_in[10];
    const float* bn_beta  = (const float*)d_in[11];
    const float* bn_mean  = (const float*)d_in[12];
    const float* bn_var   = (const float*)d_in[13];
    const float* pw1 = (const float*)d_in[14]; const float* pb1 = (const float*)d_in[15];
    const float* pw2 = (const float*)d_in[16]; const float* pb2 = (const float*)d_in[17];
    const float* cw1 = (const float*)d_in[18]; const float* cb1 = (const float*)d_in[19];
    const float* cw2 = (const float*)d_in[20]; const float* cb2 = (const float*)d_in[21];
    float* out = (float*)d_out;

    // Workspace layout (4-byte units):
    float* ws   = (float*)d_ws;
    float* dinv = ws;                                   // NN
    int*   cnt  = (int*)(ws + NN);                      // NN (hist, then cursor)
    int*   rs   = cnt + NN;                             // NN+1
    int*   tsum = rs + NN + 1;                          // 128
    int*   dbin = tsum + 128;                           // 64 (degree histogram)
    int*   dcur = dbin + 64;                            // 64 (bin alloc cursors)
    int*   perm = dcur + 64;                            // NN (degree-sorted node order)
    int*   esrc = perm + NN;                            // NE
    unsigned short* w1hi = (unsigned short*)(esrc + NE);  // 16384 each
    unsigned short* w1lo = w1hi + HID * HID;
    unsigned short* w2hi = w1lo + HID * HID;
    unsigned short* w2lo = w2hi + HID * HID;
    size_t head = (size_t)NN * 2 + (NN + 1) + 128 + 64 + 64 + NN + NE + (4 * HID * HID) / 2;
    head = (head + 3) & ~(size_t)3;                     // 16B align
    unsigned short* A = (unsigned short*)(ws + head);   // NN*HID ushort (bf16)
    unsigned short* B = A + (size_t)NN * HID;           // NN*HID ushort (bf16)
    float* pv   = (float*)(B + (size_t)NN * HID);       // 64

    const int* srcp = eidx;
    const int* dstp = eidx + NE;

    const int NB = (NE + 255) / 256;  // bucket blocks

    // ---- build CSR (by dst) + dinv + degree-binned perm; split W1/W2 + pocket ----
    hipMemsetAsync(cnt, 0, (size_t)(NN + NN + 1 + 128 + 64 + 64) * sizeof(int), stream);
    hist_kernel<<<NB, 256, 0, stream>>>(dstp, cnt);
    scan_a<<<NTILES, 256, 0, stream>>>(cnt, rs, tsum, dinv, dbin);
    scan_c<<<NTILES, 256, 0, stream>>>(rs, tsum, cnt, dbin, dcur, perm);  // cnt becomes cursor
    bucket_prep_kernel<<<NB + 65, 256, 0, stream>>>(srcp, dstp, cnt, esrc,
                                                    W1, W2, w1hi, w1lo, w2hi, w2lo,
                                                    pocket, pw1, pb1, pw2, pb2, pv, NB);
    // deterministic intra-bucket edge order (bit-stable outputs across calls)
    sort_buckets<<<(NN + 255) / 256, 256, 0, stream>>>(rs, esrc, perm);

    // ---- layer 0 fused: agg(x) -> @W0 -> BN -> ReLU -> bf16 plane A ----
    l0_fused<<<MM_TILES, 256, 0, stream>>>(x, rs, esrc, dinv, W0, b0,
                                           bn_gamma + 0 * HID, bn_beta + 0 * HID,
                                           bn_mean + 0 * HID, bn_var + 0 * HID, A);

    const int MM_BLOCKS = 1024;  // persistent, ~3 tiles/block
    const int GA_BLOCKS = (NN * 16 + 255) / 256;

    // ---- layer 1: A -> B(hl) -> A(h) ----
    mm_mfma<<<MM_BLOCKS, 256, 0, stream>>>(A, w1hi, w1lo, B);
    gather_bn<<<GA_BLOCKS, 256, 0, stream>>>(
        B, rs, esrc, dinv, b1,
        bn_gamma + 1 * HID, bn_beta + 1 * HID, bn_mean + 1 * HID, bn_var + 1 * HID, A);
    // ---- layer 2: A -> B(hl) -> A(h) ----
    mm_mfma<<<MM_BLOCKS, 256, 0, stream>>>(A, w2hi, w2lo, B);
    gather_bn<<<GA_BLOCKS, 256, 0, stream>>>(
        B, rs, esrc, dinv, b2,
        bn_gamma + 2 * HID, bn_beta + 2 * HID, bn_mean + 2 * HID, bn_var + 2 * HID, A);

    // fused pool + classifier (bf16 h)
    poolcls_kernel<<<NG, 1024, 0, stream>>>(A, batch, pv, cw1, cb1, cw2, cb2, out);
}